// Round 7
// baseline (157.309 us; speedup 1.0000x reference)
//
#include <hip/hip_runtime.h>
#include <cstdint>
#include <math.h>

// SoftmaxGaussian: out_mean/out_var over 10000 MC softmax samples with
// JAX threefry2x32-exact random draw (key(42), shape (512,16,10000)).
//
//   N = 512*16*10000 ; half = 40,960,000 = 256*16*10000
//   flat j=(b*16+k)*10000+s ; threefry block i: counters (i, i+half),
//   key (0,42) -> (z[j=i], z[j=i+half]) => one call yields (b,k,s) AND
//   (b+256,k,s).
//
// R7: R5/R6 showed VALUBusy pinned at 73% at 4 waves/SIMD regardless of
// spills: per-wave dependency stalls (erfinv fma chain + trans latency).
// Need 8 waves/SIMD (<=64 VGPR) with NO spills. Restructure: 4-lane
// cooperative rows — lane a=tid&3 owns k in {4a..4a+3}; 4 lanes share one
// sample s; softmax row-sum via 2x shfl_xor (quad DPP). Per-thread state
// shrinks 4x (acc 16 + mu/sv 16 + e 8 regs). Grid 2048 (SPLIT=8) to supply
// 8 blocks/CU. launch_bounds(256,4) = the empirical 64-VGPR cap (R2/R5) —
// now correct because the kernel fits. Numerics bit-identical per z.

typedef float f32x2 __attribute__((ext_vector_type(2)));

#define NSAMP 10000
#define HALF_N 40960000u
#define THREADS 256
#define WAVES 4

#define LOG2E 1.44269504088896340736f
#define NLN2 -0.69314718055994530942f
#define SQRT_LN2 0.83255461115769775635f

__device__ __forceinline__ uint32_t rotl32(uint32_t x, int r) {
    return (x << r) | (x >> (32 - r));  // v_alignbit_b32
}

// JAX threefry2x32, key = (0, 42)
__device__ __forceinline__ void tf2x32(uint32_t x0, uint32_t x1,
                                       uint32_t& o0, uint32_t& o1) {
    const uint32_t ks1 = 42u;
    const uint32_t ks2 = 0x1BD11BDAu ^ 42u;
    x1 += ks1;
#define TF_R(r) { x0 += x1; x1 = rotl32(x1, r); x1 ^= x0; }
    TF_R(13) TF_R(15) TF_R(26) TF_R(6)   x0 += ks1; x1 += ks2 + 1u;
    TF_R(17) TF_R(29) TF_R(16) TF_R(24)  x0 += ks2; x1 += 2u;
    TF_R(13) TF_R(15) TF_R(26) TF_R(6)                x1 += ks1 + 3u;
    TF_R(17) TF_R(29) TF_R(16) TF_R(24)  x0 += ks1; x1 += ks2 + 4u;
    TF_R(13) TF_R(15) TF_R(26) TF_R(6)   x0 += ks2; x1 += 5u;
#undef TF_R
    o0 = x0;
    o1 = x1;
}

// JAX uniform(lo=nextafter(-1,0), hi=1), packed pair; one rounding (= JAX).
__device__ __forceinline__ f32x2 u2_from_bits(uint32_t ba, uint32_t bb) {
    f32x2 f;
    f.x = __uint_as_float((ba >> 9) | 0x3F800000u);
    f.y = __uint_as_float((bb >> 9) | 0x3F800000u);
    f = f - (f32x2){1.0f, 1.0f};  // exact (Sterbenz)
    return __builtin_elementwise_fma(f, (f32x2){2.0f, 2.0f},
                                     (f32x2){-0.99999994f, -0.99999994f});
}

// XLA's ErfInv f32 (Giles 2012), branchless both-path, packed pair.
// l = log2(1-x^2) <= 0 ; w = -ln2*l ; main path w<5 <=> l > -5/ln2.
__device__ __forceinline__ f32x2 erfinv2(f32x2 x) {
    f32x2 t = __builtin_elementwise_fma(-x, x, (f32x2){1.0f, 1.0f});
    f32x2 l;
    l.x = __builtin_amdgcn_logf(t.x);
    l.y = __builtin_amdgcn_logf(t.y);
    f32x2 wm = __builtin_elementwise_fma((f32x2){NLN2, NLN2}, l,
                                         (f32x2){-2.5f, -2.5f});
#define P9(P, W, C) P = __builtin_elementwise_fma(P, W, (f32x2){C, C});
    f32x2 p1 = {2.81022636e-08f, 2.81022636e-08f};
    P9(p1, wm, 3.43273939e-07f)
    P9(p1, wm, -3.5233877e-06f)
    P9(p1, wm, -4.39150654e-06f)
    P9(p1, wm, 0.00021858087f)
    P9(p1, wm, -0.00125372503f)
    P9(p1, wm, -0.00417768164f)
    P9(p1, wm, 0.246640727f)
    P9(p1, wm, 1.50140941f)
    f32x2 sq;
    sq.x = __builtin_amdgcn_sqrtf(-l.x);
    sq.y = __builtin_amdgcn_sqrtf(-l.y);
    f32x2 wt = __builtin_elementwise_fma((f32x2){SQRT_LN2, SQRT_LN2}, sq,
                                         (f32x2){-3.0f, -3.0f});
    f32x2 p2 = {-0.000200214257f, -0.000200214257f};
    P9(p2, wt, 0.000100950558f)
    P9(p2, wt, 0.00134934322f)
    P9(p2, wt, -0.00367342844f)
    P9(p2, wt, 0.00573950773f)
    P9(p2, wt, -0.0076224613f)
    P9(p2, wt, 0.00943887047f)
    P9(p2, wt, 1.00167406f)
    P9(p2, wt, 2.83297682f)
#undef P9
    f32x2 p;
    p.x = (l.x > -7.2134752f) ? p1.x : p2.x;  // -5/ln2
    p.y = (l.y > -7.2134752f) ? p1.y : p2.y;
    return p * x;
}

__device__ __forceinline__ float qsum4(float v) {   // sum within 4-lane group
    v += __shfl_xor(v, 1);
    v += __shfl_xor(v, 2);
    return v;
}
__device__ __forceinline__ float xsum16(float v) {  // sum over lanes w/ same (l&3)
    v += __shfl_xor(v, 4);
    v += __shfl_xor(v, 8);
    v += __shfl_xor(v, 16);
    v += __shfl_xor(v, 32);
    return v;
}

// Accumulate samples [s_begin, s_end) for batch-row b (and b+256); leaves
// block-reduced partials s_fin[k*4 + {s0,q0,s1,q1}]. Lane a=tid&3 owns
// k in {4a..4a+3}; 4-lane group shares sample s = s_begin + (tid>>2) + 64*i.
// Softmax in log2 domain (s_mu/s_sv pre-scaled by log2e), no max-subtract
// (|x| <= ~15: exp2 overflow-safe).
__device__ __forceinline__ void sg_accumulate(const float* __restrict__ mean,
                                              const float* __restrict__ var,
                                              int b, int s_begin, int s_end,
                                              float (*s_mu)[16], float (*s_sv)[16],
                                              float* s_red, float* s_fin) {
    const int tid = threadIdx.x;

    if (tid < 32) {
        int h = tid >> 4, k = tid & 15;
        int bg = b + 256 * h;
        s_mu[h][k] = LOG2E * mean[bg * 16 + k];
        s_sv[h][k] = (LOG2E * 1.41421356237309515f) * sqrtf(var[bg * 16 + k]);
    }
    __syncthreads();

    const int a4 = (tid & 3) * 4;   // this lane's k base
    const int sgrp = tid >> 2;      // 0..63: s-group within block

    f32x2 mu0[2], sv0[2], mu1[2], sv1[2];
#pragma unroll
    for (int p = 0; p < 2; p++) {
        mu0[p] = *(const f32x2*)&s_mu[0][a4 + 2 * p];
        sv0[p] = *(const f32x2*)&s_sv[0][a4 + 2 * p];
        mu1[p] = *(const f32x2*)&s_mu[1][a4 + 2 * p];
        sv1[p] = *(const f32x2*)&s_sv[1][a4 + 2 * p];
    }

    f32x2 as0[2], aq0[2], as1[2], aq1[2];
#pragma unroll
    for (int p = 0; p < 2; p++) {
        as0[p] = (f32x2){0.f, 0.f}; aq0[p] = (f32x2){0.f, 0.f};
        as1[p] = (f32x2){0.f, 0.f}; aq1[p] = (f32x2){0.f, 0.f};
    }

    const uint32_t base = (uint32_t)((b * 16 + a4) * 10000);

    for (int s = s_begin + sgrp; s < s_end; s += 64) {
        f32x2 e0[2], e1[2];
#pragma unroll
        for (int p = 0; p < 2; p++) {
            uint32_t ia = base + (uint32_t)(p * 20000) + (uint32_t)s;
            uint32_t ib = ia + 10000u;
            uint32_t a0, a1, b0, b1;
            tf2x32(ia, ia + HALF_N, a0, a1);
            tf2x32(ib, ib + HALF_N, b0, b1);
            f32x2 z0 = erfinv2(u2_from_bits(a0, b0));  // batch b,     (k,k+1)
            f32x2 z1 = erfinv2(u2_from_bits(a1, b1));  // batch b+256, (k,k+1)
            e0[p] = __builtin_elementwise_fma(z0, sv0[p], mu0[p]);
            e1[p] = __builtin_elementwise_fma(z1, sv1[p], mu1[p]);
        }
#pragma unroll
        for (int p = 0; p < 2; p++) {
            e0[p].x = __builtin_amdgcn_exp2f(e0[p].x);
            e0[p].y = __builtin_amdgcn_exp2f(e0[p].y);
            e1[p].x = __builtin_amdgcn_exp2f(e1[p].x);
            e1[p].y = __builtin_amdgcn_exp2f(e1[p].y);
        }
        f32x2 q0 = e0[0] + e0[1];
        f32x2 q1 = e1[0] + e1[1];
        float r0 = qsum4(q0.x + q0.y);  // full 16-wide row sum, batch b
        float r1 = qsum4(q1.x + q1.y);  // batch b+256
        float inv0 = __builtin_amdgcn_rcpf(r0);
        float inv1 = __builtin_amdgcn_rcpf(r1);
        f32x2 iv0 = {inv0, inv0}, iv1 = {inv1, inv1};
#pragma unroll
        for (int p = 0; p < 2; p++) {
            f32x2 p0 = e0[p] * iv0;
            f32x2 p1 = e1[p] * iv1;
            as0[p] += p0; aq0[p] = __builtin_elementwise_fma(p0, p0, aq0[p]);
            as1[p] += p1; aq1[p] = __builtin_elementwise_fma(p1, p1, aq1[p]);
        }
    }

    // Cross-lane: sum the 16 per-thread scalars over the 16 lanes sharing a.
    const int lane = tid & 63, wave = tid >> 6;
    float vals[16] = { as0[0].x, aq0[0].x, as1[0].x, aq1[0].x,   // k = a4+0
                       as0[0].y, aq0[0].y, as1[0].y, aq1[0].y,   // k = a4+1
                       as0[1].x, aq0[1].x, as1[1].x, aq1[1].x,   // k = a4+2
                       as0[1].y, aq0[1].y, as1[1].y, aq1[1].y }; // k = a4+3
#pragma unroll
    for (int i = 0; i < 16; i++) {
        float r = xsum16(vals[i]);
        if (lane < 4) {  // lane == a
            int k = lane * 4 + (i >> 2);
            s_red[wave * 64 + k * 4 + (i & 3)] = r;
        }
    }
    __syncthreads();

    if (tid < 64) {
        float t = 0.f;
#pragma unroll
        for (int w = 0; w < WAVES; w++) t += s_red[w * 64 + tid];
        s_fin[tid] = t;
    }
    __syncthreads();
}

// ---- split path: 256*NCH blocks write partials to ws ----
template <int NCH>
__global__ __launch_bounds__(THREADS, 4)
void sg_partial(const float* __restrict__ mean, const float* __restrict__ var,
                float* __restrict__ ws) {
    __shared__ __attribute__((aligned(8))) float s_mu[2][16];
    __shared__ __attribute__((aligned(8))) float s_sv[2][16];
    __shared__ float s_red[WAVES * 64], s_fin[64];
    const int b = blockIdx.x / NCH;       // 0..255
    const int chunk = blockIdx.x % NCH;
    const int c0 = chunk * (NSAMP / NCH);
    sg_accumulate(mean, var, b, c0, c0 + NSAMP / NCH, s_mu, s_sv, s_red, s_fin);
    if (threadIdx.x < 64) ws[blockIdx.x * 64 + threadIdx.x] = s_fin[threadIdx.x];
}

__global__ __launch_bounds__(256)
void sg_finalize(const float* __restrict__ ws, float* __restrict__ out, int nch) {
    int t = blockIdx.x * blockDim.x + threadIdx.x;  // 0..8191
    if (t >= 8192) return;
    int k = t & 15, h = (t >> 4) & 1, b = t >> 5;
    float sum = 0.f, sq = 0.f;
    for (int c = 0; c < nch; c++) {
        const float* p = ws + ((b * nch + c) * 64 + k * 4 + 2 * h);
        sum += p[0];
        sq += p[1];
    }
    float mu = sum * (1.0f / 10000.0f);
    float vr = (sq - sum * mu) * (1.0f / 9999.0f);  // unbiased
    int bg = b + 256 * h;
    out[bg * 16 + k] = mu;
    out[8192 + bg * 16 + k] = vr;
}

// ---- fallback (ws too small): single kernel, one block per b ----
__global__ __launch_bounds__(THREADS, 4)
void sg_kernel(const float* __restrict__ mean, const float* __restrict__ var,
               float* __restrict__ out) {
    __shared__ __attribute__((aligned(8))) float s_mu[2][16];
    __shared__ __attribute__((aligned(8))) float s_sv[2][16];
    __shared__ float s_red[WAVES * 64], s_fin[64];
    const int b = blockIdx.x;
    sg_accumulate(mean, var, b, 0, NSAMP, s_mu, s_sv, s_red, s_fin);
    const int tid = threadIdx.x;
    if (tid < 32) {
        int h = tid >> 4, k = tid & 15;
        float sum = s_fin[k * 4 + 2 * h + 0];
        float sq  = s_fin[k * 4 + 2 * h + 1];
        float mu = sum * (1.0f / 10000.0f);
        float vr = (sq - sum * mu) * (1.0f / 9999.0f);
        int bg = b + 256 * h;
        out[bg * 16 + k] = mu;
        out[8192 + bg * 16 + k] = vr;
    }
}

extern "C" void kernel_launch(void* const* d_in, const int* in_sizes, int n_in,
                              void* d_out, int out_size, void* d_ws, size_t ws_size,
                              hipStream_t stream) {
    const float* mean = (const float*)d_in[0];
    const float* var  = (const float*)d_in[1];
    float* out = (float*)d_out;
    float* ws = (float*)d_ws;
    if (ws_size >= 256 * 8 * 64 * sizeof(float)) {          // 512 KiB
        sg_partial<8><<<256 * 8, THREADS, 0, stream>>>(mean, var, ws);
        sg_finalize<<<32, 256, 0, stream>>>(ws, out, 8);
    } else if (ws_size >= 256 * 4 * 64 * sizeof(float)) {   // 256 KiB
        sg_partial<4><<<256 * 4, THREADS, 0, stream>>>(mean, var, ws);
        sg_finalize<<<32, 256, 0, stream>>>(ws, out, 4);
    } else {
        sg_kernel<<<256, THREADS, 0, stream>>>(mean, var, out);
    }
}